// Round 2
// baseline (36994.800 us; speedup 1.0000x reference)
//
#include <hip/hip_runtime.h>
#include <hip/hip_bf16.h>
#include <stdint.h>
#include <math.h>

// ---------------- threefry2x32 (JAX-exact) ----------------
__device__ __forceinline__ void tf2x32(uint32_t k0, uint32_t k1,
                                       uint32_t x0, uint32_t x1,
                                       uint32_t* o0, uint32_t* o1) {
  uint32_t ks0 = k0, ks1 = k1, ks2 = k0 ^ k1 ^ 0x1BD11BDAu;
  x0 += ks0; x1 += ks1;
  const int R[8] = {13,15,26,6, 17,29,16,24};
#pragma unroll
  for (int g = 0; g < 5; ++g) {
    const int base = (g & 1) ? 4 : 0;
#pragma unroll
    for (int j = 0; j < 4; ++j) {
      int r = R[base + j];
      x0 += x1;
      x1 = (x1 << r) | (x1 >> (32 - r));
      x1 ^= x0;
    }
    switch (g) {
      case 0: x0 += ks1; x1 += ks2 + 1u; break;
      case 1: x0 += ks2; x1 += ks0 + 2u; break;
      case 2: x0 += ks0; x1 += ks1 + 3u; break;
      case 3: x0 += ks1; x1 += ks2 + 4u; break;
      case 4: x0 += ks2; x1 += ks0 + 5u; break;
    }
  }
  *o0 = x0; *o1 = x1;
}

__device__ __forceinline__ float gumbel_from_bits(uint32_t bits) {
  float u = __uint_as_float((bits >> 9) | 0x3f800000u) - 1.0f;
  if (u == 0.0f) u = 1.1754943508222875e-38f;  // finfo(f32).tiny
  return -logf(-logf(u));
}

__device__ __forceinline__ float sigf(float x) { return 1.0f / (1.0f + expf(-x)); }

// ---------------- init / embed / copy ----------------
__global__ void init_state(const float* __restrict__ h0, const float* __restrict__ c0,
                           float* __restrict__ u0, float* __restrict__ cbuf,
                           float* __restrict__ stack, int* __restrict__ depth) {
  int i = blockIdx.x * blockDim.x + threadIdx.x;  // grid covers 65536
  if (i < 65536) {
    int b = i >> 11, k = i & 2047;
    u0[i] = (k < 1024) ? h0[b * 1024 + k] : 0.0f;   // [h0, si=0]
    stack[i] = 0.0f;
  }
  if (i < 32768) cbuf[i] = c0[i];
  if (i < 32) depth[i] = 0;
}

__global__ void embed_kernel(const int* __restrict__ toks, const float* __restrict__ embW,
                             float* __restrict__ emb) {
  int row = blockIdx.x;            // 0..4095  (t*32+b)
  int tid = threadIdx.x;           // 128 threads, float4 each
  int tk = toks[row];
  float4 v = ((const float4*)(embW + (size_t)tk * 512))[tid];
  ((float4*)(emb + (size_t)row * 512))[tid] = v;
}

__global__ void final_copy(const float* __restrict__ u0, const float* __restrict__ cbuf,
                           float* __restrict__ out) {
  int i = blockIdx.x * blockDim.x + threadIdx.x;  // 32768
  int b = i >> 10, k = i & 1023;
  out[131072000u + i] = u0[(size_t)b * 2048 + k];
  out[131072000u + 32768u + i] = cbuf[i];
}

// ---------------- per-step gates GEMM (fp32) ----------------
// G layout per row b (32 rows x 12800): [r 0..4095 | s 4096..8191 | m 8192..12287 | z 12288..12799]
__global__ __launch_bounds__(256) void step_gemm(
    int t, const float* __restrict__ u, const float* __restrict__ emb, float* __restrict__ G,
    const float* __restrict__ rWih, const float* __restrict__ rWhh, const float* __restrict__ rb,
    const float* __restrict__ sWih, const float* __restrict__ sWhh, const float* __restrict__ sb,
    const float* __restrict__ mWih, const float* __restrict__ mWhh, const float* __restrict__ mb,
    const float* __restrict__ piW1, const float* __restrict__ pib1) {
  __shared__ float As[32][33];
  __shared__ float Ws[32][33];
  int bid = blockIdx.x, tid = threadIdx.x;
  int tx = tid & 31, ty = tid >> 5;
  const float* embt = emb + (size_t)t * 32 * 512;
  const float* Ap[3]; const float* Wp[3];
  int Ast[3], Wst[3], Kp[3], np, gcol0;
  const float* bias;
  if (bid < 128) {
    int c0 = bid * 32; gcol0 = c0; np = 2; bias = rb + c0;
    Ap[0] = embt; Ast[0] = 512;  Wp[0] = rWih + (size_t)c0 * 512;  Wst[0] = 512;  Kp[0] = 512;
    Ap[1] = u;    Ast[1] = 2048; Wp[1] = rWhh + (size_t)c0 * 1024; Wst[1] = 1024; Kp[1] = 1024;
  } else if (bid < 256) {
    int c0 = (bid - 128) * 32; gcol0 = 4096 + c0; np = 2; bias = sb + c0;
    Ap[0] = embt; Ast[0] = 512;  Wp[0] = sWih + (size_t)c0 * 512;  Wst[0] = 512;  Kp[0] = 512;
    Ap[1] = u;    Ast[1] = 2048; Wp[1] = sWhh + (size_t)c0 * 1024; Wst[1] = 1024; Kp[1] = 1024;
  } else if (bid < 384) {
    int c0 = (bid - 256) * 32; gcol0 = 8192 + c0; np = 3; bias = mb + c0;
    Ap[0] = embt;     Ast[0] = 512;  Wp[0] = mWih + (size_t)c0 * 1536;       Wst[0] = 1536; Kp[0] = 512;
    Ap[1] = u;        Ast[1] = 2048; Wp[1] = mWhh + (size_t)c0 * 1024;       Wst[1] = 1024; Kp[1] = 1024;
    Ap[2] = u + 1024; Ast[2] = 2048; Wp[2] = mWih + (size_t)c0 * 1536 + 512; Wst[2] = 1536; Kp[2] = 1024;
  } else {
    int c0 = (bid - 384) * 32; gcol0 = 12288 + c0; np = 2; bias = pib1 + c0;
    Ap[0] = u;    Ast[0] = 2048; Wp[0] = piW1 + (size_t)c0 * 1536;        Wst[0] = 1536; Kp[0] = 1024;
    Ap[1] = embt; Ast[1] = 512;  Wp[1] = piW1 + (size_t)c0 * 1536 + 1024; Wst[1] = 1536; Kp[1] = 512;
  }
  float acc[4] = {0.f, 0.f, 0.f, 0.f};
  for (int p = 0; p < np; ++p) {
    const float* Ab = Ap[p]; const float* Wb = Wp[p];
    int as = Ast[p], wsd = Wst[p], KK = Kp[p];
    for (int k0 = 0; k0 < KK; k0 += 32) {
      __syncthreads();
#pragma unroll
      for (int q = 0; q < 4; ++q) {
        int idx = tid + q * 256;
        int rr = idx >> 5, kk = idx & 31;
        As[rr][kk] = Ab[(size_t)rr * as + k0 + kk];
        Ws[rr][kk] = Wb[(size_t)rr * wsd + k0 + kk];
      }
      __syncthreads();
#pragma unroll
      for (int kk = 0; kk < 32; ++kk) {
        float wv = Ws[tx][kk];
        acc[0] += As[ty][kk] * wv;
        acc[1] += As[ty + 8][kk] * wv;
        acc[2] += As[ty + 16][kk] * wv;
        acc[3] += As[ty + 24][kk] * wv;
      }
    }
  }
  float bv = bias[tx];
#pragma unroll
  for (int i = 0; i < 4; ++i)
    G[(size_t)(ty + 8 * i) * 12800 + gcol0 + tx] = acc[i] + bv;
}

// ---------------- per-step pointwise: LN/logits/sample + LSTM cells + stack ----------------
__global__ __launch_bounds__(256) void step_pointwise(
    int t, const float* __restrict__ G, float* __restrict__ u_next,
    float* __restrict__ cbuf, float* __restrict__ stack, int* __restrict__ depth,
    float* __restrict__ outs,
    const float* __restrict__ pilng, const float* __restrict__ pilnb,
    const float* __restrict__ piW2, const float* __restrict__ pib2) {
  int b = blockIdx.x, tid = threadIdx.x;
  __shared__ float sred[256];
  __shared__ float slog[3];
  __shared__ float sb_[2];
  const float* Gb = G + (size_t)b * 12800;
  const float* zr = Gb + 12288;
  float z0 = zr[tid], z1 = zr[tid + 256];
  sred[tid] = z0 + z1; __syncthreads();
  for (int s = 128; s > 0; s >>= 1) { if (tid < s) sred[tid] += sred[tid + s]; __syncthreads(); }
  float mu = sred[0] * (1.0f / 512.0f); __syncthreads();
  float d0 = z0 - mu, d1 = z1 - mu;
  sred[tid] = d0 * d0 + d1 * d1; __syncthreads();
  for (int s = 128; s > 0; s >>= 1) { if (tid < s) sred[tid] += sred[tid + s]; __syncthreads(); }
  float rstd = rsqrtf(sred[0] * (1.0f / 512.0f) + 1e-5f); __syncthreads();
  float l0 = fmaxf(d0 * rstd * pilng[tid] + pilnb[tid], 0.0f);
  float l1 = fmaxf(d1 * rstd * pilng[tid + 256] + pilnb[tid + 256], 0.0f);
  for (int kk = 0; kk < 3; ++kk) {
    sred[tid] = l0 * piW2[kk * 512 + tid] + l1 * piW2[kk * 512 + tid + 256];
    __syncthreads();
    for (int s = 128; s > 0; s >>= 1) { if (tid < s) sred[tid] += sred[tid + s]; __syncthreads(); }
    if (tid == 0) slog[kk] = sred[0];
    __syncthreads();
  }
  if (tid == 0) {
    int dcur = depth[b];
    float lg[3];
    for (int kk = 0; kk < 3; ++kk) lg[kk] = slog[kk] + pib2[kk];
    if (dcur >= 2) lg[0] = -INFINITY;   // mask push when stack full
    if (dcur == 0) lg[2] = -INFINITY;   // mask merge when empty
    // ---- jax_threefry_partitionable=True (default in JAX >= 0.4.30) ----
    // split(key(42), 128): iota_2x32 counts -> key_t = both words of
    // threefry(0,42; hi=0, lo=t)
    uint32_t kt0, kt1;
    tf2x32(0u, 42u, 0u, (uint32_t)t, &kt0, &kt1);
    // random_bits(key_t, 32, (32,3)): bits[j] = o0 ^ o1 of
    // threefry(kt0,kt1; hi=0, lo=j), j = 3*b + kk
    for (int kk = 0; kk < 3; ++kk) {
      uint32_t j = (uint32_t)(3 * b + kk);
      uint32_t o0, o1;
      tf2x32(kt0, kt1, 0u, j, &o0, &o1);
      lg[kk] += gumbel_from_bits(o0 ^ o1);
    }
    int a = 0; float best = lg[0];
    if (lg[1] > best) { best = lg[1]; a = 1; }
    if (lg[2] > best) { a = 2; }
    sb_[0] = (float)a; sb_[1] = (float)dcur;
  }
  __syncthreads();
  int a = (int)sb_[0], dcur = (int)sb_[1];
  int dnew = dcur + ((a == 0) ? 1 : 0) - ((a == 2) ? 1 : 0);
#pragma unroll
  for (int q = 0; q < 4; ++q) {
    int k = tid + q * 256;
    float ir = Gb[k],        fr = Gb[1024 + k],  gr = Gb[2048 + k],  orr = Gb[3072 + k];
    float is = Gb[4096 + k], fs = Gb[5120 + k],  gs = Gb[6144 + k],  os  = Gb[7168 + k];
    float im = Gb[8192 + k], fm = Gb[9216 + k],  gm = Gb[10240 + k], om  = Gb[11264 + k];
    float cold = cbuf[b * 1024 + k];
    float crn = sigf(fr) * cold + sigf(ir) * tanhf(gr); float hrn = sigf(orr) * tanhf(crn);
    float csn = sigf(fs) * cold + sigf(is) * tanhf(gs); float hsn = sigf(os)  * tanhf(csn);
    float cmn = sigf(fm) * cold + sigf(im) * tanhf(gm); float hmn = sigf(om)  * tanhf(cmn);
    float hn = (a == 0) ? hsn : ((a == 1) ? hrn : hmn);
    float cn = (a == 0) ? csn : ((a == 1) ? crn : cmn);
    cbuf[b * 1024 + k] = cn;
    u_next[(size_t)b * 2048 + k] = hn;
    outs[(size_t)t * 32768 + b * 1024 + k] = hn;
    float si;
    if (a == 0) { stack[(size_t)(b * 2 + dcur) * 1024 + k] = hsn; si = hsn; }
    else si = (dnew > 0) ? stack[(size_t)(b * 2 + (dnew - 1)) * 1024 + k] : 0.0f;
    u_next[(size_t)b * 2048 + 1024 + k] = si;
  }
  if (tid == 0) depth[b] = dnew;
}

// ---------------- epilogue GEMMs: C = A(M,K) @ W(N,K)^T + bias [+ tanh-BN] ----------------
template <int EPI>
__global__ __launch_bounds__(256) void gemm_epi(
    const float* __restrict__ A, const float* __restrict__ W,
    const float* __restrict__ bias, float* __restrict__ C,
    int K, int N, const float* __restrict__ g, const float* __restrict__ bb, float invS) {
  __shared__ float Asb[32][68];
  __shared__ float Bsb[32][68];
  int tid = threadIdx.x;
  int tx = tid & 15, ty = tid >> 4;
  int m0 = blockIdx.y * 64, n0 = blockIdx.x * 64;
  int r = tid >> 3;
  int kb = (tid & 7) * 4;
  float acc[4][4] = {};
  for (int k0 = 0; k0 < K; k0 += 32) {
    __syncthreads();
    float4 a0 = *(const float4*)(A + (size_t)(m0 + r) * K + k0 + kb);
    float4 a1 = *(const float4*)(A + (size_t)(m0 + r + 32) * K + k0 + kb);
    float4 b0 = *(const float4*)(W + (size_t)(n0 + r) * K + k0 + kb);
    float4 b1 = *(const float4*)(W + (size_t)(n0 + r + 32) * K + k0 + kb);
    Asb[kb + 0][r] = a0.x; Asb[kb + 1][r] = a0.y; Asb[kb + 2][r] = a0.z; Asb[kb + 3][r] = a0.w;
    Asb[kb + 0][r + 32] = a1.x; Asb[kb + 1][r + 32] = a1.y; Asb[kb + 2][r + 32] = a1.z; Asb[kb + 3][r + 32] = a1.w;
    Bsb[kb + 0][r] = b0.x; Bsb[kb + 1][r] = b0.y; Bsb[kb + 2][r] = b0.z; Bsb[kb + 3][r] = b0.w;
    Bsb[kb + 0][r + 32] = b1.x; Bsb[kb + 1][r + 32] = b1.y; Bsb[kb + 2][r + 32] = b1.z; Bsb[kb + 3][r + 32] = b1.w;
    __syncthreads();
#pragma unroll
    for (int kk = 0; kk < 32; ++kk) {
      float4 av = *(const float4*)&Asb[kk][ty * 4];
      float4 bv = *(const float4*)&Bsb[kk][tx * 4];
      float aa[4] = {av.x, av.y, av.z, av.w};
      float bw[4] = {bv.x, bv.y, bv.z, bv.w};
#pragma unroll
      for (int i = 0; i < 4; ++i)
#pragma unroll
        for (int j = 0; j < 4; ++j) acc[i][j] += aa[i] * bw[j];
    }
  }
#pragma unroll
  for (int i = 0; i < 4; ++i) {
    int row = m0 + ty * 4 + i;
#pragma unroll
    for (int j = 0; j < 4; ++j) {
      int col = n0 + tx * 4 + j;
      float v = acc[i][j] + bias[col];
      if (EPI) v = tanhf(v * invS * g[col] + bb[col]);
      C[(size_t)row * N + col] = v;
    }
  }
}

// ---------------- launcher ----------------
extern "C" void kernel_launch(void* const* d_in, const int* in_sizes, int n_in,
                              void* d_out, int out_size, void* d_ws, size_t ws_size,
                              hipStream_t stream) {
  const int*   tokens = (const int*)d_in[0];
  const float* h0    = (const float*)d_in[1];
  const float* c0    = (const float*)d_in[2];
  const float* embW  = (const float*)d_in[3];
  const float* rWih  = (const float*)d_in[4];
  const float* rWhh  = (const float*)d_in[5];
  const float* rb    = (const float*)d_in[6];
  const float* sWih  = (const float*)d_in[7];
  const float* sWhh  = (const float*)d_in[8];
  const float* sb    = (const float*)d_in[9];
  const float* mWih  = (const float*)d_in[10];
  const float* mWhh  = (const float*)d_in[11];
  const float* mb    = (const float*)d_in[12];
  const float* piW1  = (const float*)d_in[13];
  const float* pib1  = (const float*)d_in[14];
  const float* pilng = (const float*)d_in[15];
  const float* pilnb = (const float*)d_in[16];
  const float* piW2  = (const float*)d_in[17];
  const float* pib2  = (const float*)d_in[18];
  const float* predW = (const float*)d_in[19];
  const float* predb = (const float*)d_in[20];
  const float* bng   = (const float*)d_in[21];
  const float* bnb   = (const float*)d_in[22];
  const float* decW  = (const float*)d_in[23];
  const float* decb  = (const float*)d_in[24];
  float* out = (float*)d_out;
  float* ws  = (float*)d_ws;

  float* emb   = ws;                    // 4096*512      = 2,097,152
  float* u0    = emb + 2097152;         // 32*2048       =    65,536
  float* u1    = u0 + 65536;            //                    65,536
  float* cbuf  = u1 + 65536;            // 32*1024       =    32,768
  float* stack = cbuf + 32768;          // 32*2*1024     =    65,536
  float* G     = stack + 65536;         // 32*12800      =   409,600
  float* outs  = G + 409600;            // 4096*1024     = 4,194,304
  float* yt    = outs + 4194304;        // 4096*512      = 2,097,152
  int*   depth = (int*)(yt + 2097152);  // 32 ints

  init_state<<<dim3(256), dim3(256), 0, stream>>>(h0, c0, u0, cbuf, stack, depth);
  embed_kernel<<<dim3(4096), dim3(128), 0, stream>>>(tokens, embW, emb);

  for (int t = 0; t < 128; ++t) {
    float* ucur = (t & 1) ? u1 : u0;
    float* unxt = (t & 1) ? u0 : u1;
    step_gemm<<<dim3(400), dim3(256), 0, stream>>>(
        t, ucur, emb, G, rWih, rWhh, rb, sWih, sWhh, sb, mWih, mWhh, mb, piW1, pib1);
    step_pointwise<<<dim3(32), dim3(256), 0, stream>>>(
        t, G, unxt, cbuf, stack, depth, outs, pilng, pilnb, piW2, pib2);
  }

  float invS = 1.0f / sqrtf(1.0f + 1e-5f);
  // y = tanh((outs @ predW^T + predb) * invS * bn_g + bn_b)  -> yt (4096,512)
  gemm_epi<1><<<dim3(8, 64), dim3(256), 0, stream>>>(outs, predW, predb, yt, 1024, 512, bng, bnb, invS);
  // dec = yt @ decW^T + decb -> out (4096,32000)
  gemm_epi<0><<<dim3(500, 64), dim3(256), 0, stream>>>(yt, decW, decb, out, 512, 32000, bng, bnb, invS);
  final_copy<<<dim3(128), dim3(256), 0, stream>>>(u0, cbuf, out);
}

// Round 3
// 7839.991 us; speedup vs baseline: 4.7187x; 4.7187x over previous
//
#include <hip/hip_runtime.h>
#include <hip/hip_bf16.h>
#include <stdint.h>
#include <math.h>

using s16x8 = __attribute__((ext_vector_type(8))) short;
using f32x4 = __attribute__((ext_vector_type(4))) float;

// ---------------- threefry2x32 (JAX-exact, partitionable) ----------------
__device__ __forceinline__ void tf2x32(uint32_t k0, uint32_t k1,
                                       uint32_t x0, uint32_t x1,
                                       uint32_t* o0, uint32_t* o1) {
  uint32_t ks0 = k0, ks1 = k1, ks2 = k0 ^ k1 ^ 0x1BD11BDAu;
  x0 += ks0; x1 += ks1;
  const int R[8] = {13,15,26,6, 17,29,16,24};
#pragma unroll
  for (int g = 0; g < 5; ++g) {
    const int base = (g & 1) ? 4 : 0;
#pragma unroll
    for (int j = 0; j < 4; ++j) {
      int r = R[base + j];
      x0 += x1;
      x1 = (x1 << r) | (x1 >> (32 - r));
      x1 ^= x0;
    }
    switch (g) {
      case 0: x0 += ks1; x1 += ks2 + 1u; break;
      case 1: x0 += ks2; x1 += ks0 + 2u; break;
      case 2: x0 += ks0; x1 += ks1 + 3u; break;
      case 3: x0 += ks1; x1 += ks2 + 4u; break;
      case 4: x0 += ks2; x1 += ks0 + 5u; break;
    }
  }
  *o0 = x0; *o1 = x1;
}

__device__ __forceinline__ float gumbel_from_bits(uint32_t bits) {
  float u = __uint_as_float((bits >> 9) | 0x3f800000u) - 1.0f;
  if (u == 0.0f) u = 1.1754943508222875e-38f;  // finfo(f32).tiny
  return -logf(-logf(u));
}

__device__ __forceinline__ float sigf(float x) { return 1.0f / (1.0f + expf(-x)); }

__device__ __forceinline__ unsigned short f2bf(float f) {
  unsigned u = __float_as_uint(f);
  unsigned r = (u + 0x7fffu + ((u >> 16) & 1u)) >> 16;
  return (unsigned short)r;
}

__device__ __forceinline__ float blk_sum(float v, volatile float* s4, int tid) {
#pragma unroll
  for (int o = 1; o < 64; o <<= 1) v += __shfl_xor(v, o, 64);
  __syncthreads();
  if ((tid & 63) == 0) s4[tid >> 6] = v;
  __syncthreads();
  return s4[0] + s4[1] + s4[2] + s4[3];
}

// ---------------- init / embed / copy / convert ----------------
__global__ void init_state(const float* __restrict__ h0, const float* __restrict__ c0,
                           float* __restrict__ u0, float* __restrict__ cbuf,
                           float* __restrict__ stack, int* __restrict__ depth) {
  int i = blockIdx.x * blockDim.x + threadIdx.x;  // 65536
  if (i < 65536) {
    int b = i >> 11, k = i & 2047;
    u0[i] = (k < 1024) ? h0[b * 1024 + k] : 0.0f;   // [h0, si=0]
    stack[i] = 0.0f;
  }
  if (i < 32768) cbuf[i] = c0[i];
  if (i < 32) depth[i] = 0;
}

__global__ void embed_kernel(const int* __restrict__ toks, const float* __restrict__ embW,
                             float* __restrict__ emb) {
  int row = blockIdx.x;            // t*32+b
  int tid = threadIdx.x;           // 128 threads, float4 each
  int tk = toks[row];
  float4 v = ((const float4*)(embW + (size_t)tk * 512))[tid];
  ((float4*)(emb + (size_t)row * 512))[tid] = v;
}

__global__ void final_copy(const float* __restrict__ u0, const float* __restrict__ cbuf,
                           float* __restrict__ out) {
  int i = blockIdx.x * blockDim.x + threadIdx.x;  // 32768
  int b = i >> 10, k = i & 1023;
  out[131072000u + i] = u0[(size_t)b * 2048 + k];
  out[131072000u + 32768u + i] = cbuf[i];
}

__global__ void to_bf16(const float* __restrict__ s, unsigned short* __restrict__ d, int n4) {
  int i = blockIdx.x * blockDim.x + threadIdx.x;
  if (i < n4) {
    float4 v = *(const float4*)(s + (size_t)i * 4);
    ushort4 o;
    o.x = f2bf(v.x); o.y = f2bf(v.y); o.z = f2bf(v.z); o.w = f2bf(v.w);
    *(ushort4*)(d + (size_t)i * 4) = o;
  }
}

// ---------------- per-step gates GEMM (fp32, partial K-split) ----------------
// Virtual A (32 x 2560) = [emb_t(512) | h(1024) | si(1024)]; G cols (12800):
// [r 0..4095 | s 4096..8191 | m 8192..12287 | z 12288..12799]
__global__ __launch_bounds__(128) void gates_gemm(
    int t, const float* __restrict__ u, const float* __restrict__ emb,
    float* __restrict__ Gpart,
    const float* __restrict__ rWih, const float* __restrict__ rWhh,
    const float* __restrict__ sWih, const float* __restrict__ sWhh,
    const float* __restrict__ mWih, const float* __restrict__ mWhh,
    const float* __restrict__ piW1) {
  __shared__ float As2[32][36];   // [k][m]
  __shared__ float Ws2[32][68];   // [k][n]
  int tid = threadIdx.x;
  int nt = blockIdx.x, js = blockIdx.y;
  int col0 = nt << 6;
  int seg = col0 >> 12;            // 0..3 (12288..12799 -> 3)
  int c0 = col0 - (seg << 12);
  int nbkTot = (seg == 2) ? 80 : 48;
  int per = nbkTot >> 2;
  int bk0 = js * per, bk1 = bk0 + per;
  const float* embt = emb + (size_t)t * 16384;
  int tx = tid & 15, ty = tid >> 4;
  float acc[4][4] = {};
  for (int bk = bk0; bk < bk1; ++bk) {
    int k0 = bk << 5;
    // weight piece for this 32-K tile
    const float* wb; int wlen, woff;
    if (seg == 0)      { if (k0 < 512) { wb = rWih; wlen = 512;  woff = k0; }
                         else          { wb = rWhh; wlen = 1024; woff = k0 - 512; } }
    else if (seg == 1) { if (k0 < 512) { wb = sWih; wlen = 512;  woff = k0; }
                         else          { wb = sWhh; wlen = 1024; woff = k0 - 512; } }
    else if (seg == 2) { if (k0 < 512)       { wb = mWih; wlen = 1536; woff = k0; }
                         else if (k0 < 1536) { wb = mWhh; wlen = 1024; woff = k0 - 512; }
                         else                { wb = mWih; wlen = 1536; woff = k0 - 1024; } }
    else               { if (k0 < 512) { wb = piW1; wlen = 1536; woff = k0 + 1024; }
                         else          { wb = piW1; wlen = 1536; woff = k0 - 512; } }
    const float* ab; int alen, aoff;
    if (k0 < 512) { ab = embt; alen = 512;  aoff = k0; }
    else          { ab = u;    alen = 2048; aoff = k0 - 512; }
    __syncthreads();
#pragma unroll
    for (int q = 0; q < 4; ++q) {
      int idx = tid + (q << 7);                 // 0..511
      int row = idx >> 3, kk = (idx & 7) << 2;
      float4 wv = *(const float4*)(wb + (size_t)(c0 + row) * wlen + woff + kk);
      Ws2[kk + 0][row] = wv.x; Ws2[kk + 1][row] = wv.y;
      Ws2[kk + 2][row] = wv.z; Ws2[kk + 3][row] = wv.w;
    }
#pragma unroll
    for (int q = 0; q < 2; ++q) {
      int idx = tid + (q << 7);                 // 0..255
      int m = idx >> 3, kk = (idx & 7) << 2;
      float4 av = *(const float4*)(ab + (size_t)m * alen + aoff + kk);
      As2[kk + 0][m] = av.x; As2[kk + 1][m] = av.y;
      As2[kk + 2][m] = av.z; As2[kk + 3][m] = av.w;
    }
    __syncthreads();
#pragma unroll
    for (int k = 0; k < 32; ++k) {
      float4 a = *(const float4*)&As2[k][ty << 2];
      float4 w = *(const float4*)&Ws2[k][tx << 2];
      acc[0][0] += a.x * w.x; acc[0][1] += a.x * w.y; acc[0][2] += a.x * w.z; acc[0][3] += a.x * w.w;
      acc[1][0] += a.y * w.x; acc[1][1] += a.y * w.y; acc[1][2] += a.y * w.z; acc[1][3] += a.y * w.w;
      acc[2][0] += a.z * w.x; acc[2][1] += a.z * w.y; acc[2][2] += a.z * w.z; acc[2][3] += a.z * w.w;
      acc[3][0] += a.w * w.x; acc[3][1] += a.w * w.y; acc[3][2] += a.w * w.z; acc[3][3] += a.w * w.w;
    }
  }
  float* gout = Gpart + (size_t)js * 409600 + col0 + (tx << 2);
#pragma unroll
  for (int r = 0; r < 4; ++r) {
    float4 v = make_float4(acc[r][0], acc[r][1], acc[r][2], acc[r][3]);
    *(float4*)(gout + (size_t)((ty << 2) + r) * 12800) = v;
  }
}

// ---------------- per-step pointwise: LN/logits/sample + LSTM cells + stack ----------------
__global__ __launch_bounds__(256) void step_pointwise(
    int t, const float* __restrict__ Gp, float* __restrict__ u_next,
    float* __restrict__ cbuf, float* __restrict__ stack, int* __restrict__ depth,
    unsigned short* __restrict__ outsb,
    const float* __restrict__ rb, const float* __restrict__ sbv,
    const float* __restrict__ mb, const float* __restrict__ pib1,
    const float* __restrict__ pilng, const float* __restrict__ pilnb,
    const float* __restrict__ piW2, const float* __restrict__ pib2) {
  int b = blockIdx.x, tid = threadIdx.x;
  __shared__ float s4[4];
  __shared__ int sact[2];
  const float* Gb = Gp + (size_t)b * 12800;
#define PART(col) (Gb[(col)] + Gb[409600 + (col)] + Gb[819200 + (col)] + Gb[1228800 + (col)])
  float z0 = PART(12288 + tid) + pib1[tid];
  float z1 = PART(12544 + tid) + pib1[tid + 256];
  float mu = blk_sum(z0 + z1, s4, tid) * (1.0f / 512.0f);
  float d0 = z0 - mu, d1 = z1 - mu;
  float var = blk_sum(d0 * d0 + d1 * d1, s4, tid) * (1.0f / 512.0f);
  float rstd = rsqrtf(var + 1e-5f);
  float l0 = fmaxf(d0 * rstd * pilng[tid] + pilnb[tid], 0.0f);
  float l1 = fmaxf(d1 * rstd * pilng[tid + 256] + pilnb[tid + 256], 0.0f);
  float lg[3];
#pragma unroll
  for (int kk = 0; kk < 3; ++kk)
    lg[kk] = blk_sum(l0 * piW2[kk * 512 + tid] + l1 * piW2[kk * 512 + tid + 256], s4, tid);
  if (tid == 0) {
    int dcur = depth[b];
#pragma unroll
    for (int kk = 0; kk < 3; ++kk) lg[kk] += pib2[kk];
    if (dcur >= 2) lg[0] = -INFINITY;   // mask push when stack full
    if (dcur == 0) lg[2] = -INFINITY;   // mask merge when empty
    // split(key(42),128): key_t = threefry(0,42; 0, t)
    uint32_t kt0, kt1;
    tf2x32(0u, 42u, 0u, (uint32_t)t, &kt0, &kt1);
    // bits[j] = o0^o1 of threefry(kt; 0, j), j = 3*b + kk
#pragma unroll
    for (int kk = 0; kk < 3; ++kk) {
      uint32_t o0, o1;
      tf2x32(kt0, kt1, 0u, (uint32_t)(3 * b + kk), &o0, &o1);
      lg[kk] += gumbel_from_bits(o0 ^ o1);
    }
    int a = 0; float best = lg[0];
    if (lg[1] > best) { best = lg[1]; a = 1; }
    if (lg[2] > best) { a = 2; }
    sact[0] = a; sact[1] = dcur;
  }
  __syncthreads();
  int a = sact[0], dcur = sact[1];
  int dnew = dcur + ((a == 0) ? 1 : 0) - ((a == 2) ? 1 : 0);
#pragma unroll
  for (int q = 0; q < 4; ++q) {
    int k = tid + (q << 8);
    float ir = PART(k)        + rb[k],        fr = PART(1024 + k)  + rb[1024 + k];
    float gr = PART(2048 + k) + rb[2048 + k], orr = PART(3072 + k) + rb[3072 + k];
    float is = PART(4096 + k) + sbv[k],       fs = PART(5120 + k)  + sbv[1024 + k];
    float gs = PART(6144 + k) + sbv[2048 + k], os = PART(7168 + k) + sbv[3072 + k];
    float im = PART(8192 + k) + mb[k],        fm = PART(9216 + k)  + mb[1024 + k];
    float gm = PART(10240 + k) + mb[2048 + k], om = PART(11264 + k) + mb[3072 + k];
    float cold = cbuf[b * 1024 + k];
    float crn = sigf(fr) * cold + sigf(ir) * tanhf(gr); float hrn = sigf(orr) * tanhf(crn);
    float csn = sigf(fs) * cold + sigf(is) * tanhf(gs); float hsn = sigf(os)  * tanhf(csn);
    float cmn = sigf(fm) * cold + sigf(im) * tanhf(gm); float hmn = sigf(om)  * tanhf(cmn);
    float hn = (a == 0) ? hsn : ((a == 1) ? hrn : hmn);
    float cn = (a == 0) ? csn : ((a == 1) ? crn : cmn);
    cbuf[b * 1024 + k] = cn;
    u_next[(size_t)b * 2048 + k] = hn;
    outsb[(size_t)t * 32768 + b * 1024 + k] = f2bf(hn);
    float si;
    if (a == 0) { stack[(size_t)(b * 2 + dcur) * 1024 + k] = hsn; si = hsn; }
    else si = (dnew > 0) ? stack[(size_t)(b * 2 + (dnew - 1)) * 1024 + k] : 0.0f;
    u_next[(size_t)b * 2048 + 1024 + k] = si;
  }
#undef PART
  if (tid == 0) depth[b] = dnew;
}

// ---------------- bf16 MFMA GEMM: C = A(M,K) @ W(N,K)^T + bias [+ tanh-BN -> bf16] ----------------
template <int EPI>
__global__ __launch_bounds__(256) void mfma_gemm(
    const unsigned short* __restrict__ A, const unsigned short* __restrict__ W,
    const float* __restrict__ bias, int K, int N,
    float* __restrict__ Cf, unsigned short* __restrict__ Cb,
    const float* __restrict__ g, const float* __restrict__ bb, float invS) {
  __shared__ unsigned short As[128][40];
  __shared__ unsigned short Bs[128][40];
  int tid = threadIdx.x;
  int m0 = blockIdx.y << 7, n0 = blockIdx.x << 7;
  int wid = tid >> 6, lane = tid & 63;
  int wm = (wid >> 1) << 6, wn = (wid & 1) << 6;
  int lr = lane & 15, lk = (lane >> 4) << 3;
  f32x4 acc[4][4] = {};
  for (int k0 = 0; k0 < K; k0 += 32) {
    __syncthreads();
#pragma unroll
    for (int q = 0; q < 2; ++q) {
      int idx = tid + (q << 8);                // 0..511
      int row = idx >> 2, k8 = (idx & 3) << 3;
      *(s16x8*)&As[row][k8] = *(const s16x8*)(A + (size_t)(m0 + row) * K + k0 + k8);
      *(s16x8*)&Bs[row][k8] = *(const s16x8*)(W + (size_t)(n0 + row) * K + k0 + k8);
    }
    __syncthreads();
    s16x8 af[4], bw[4];
#pragma unroll
    for (int i = 0; i < 4; ++i) {
      af[i] = *(const s16x8*)&As[wm + (i << 4) + lr][lk];
      bw[i] = *(const s16x8*)&Bs[wn + (i << 4) + lr][lk];
    }
#pragma unroll
    for (int i = 0; i < 4; ++i)
#pragma unroll
      for (int j = 0; j < 4; ++j)
        acc[i][j] = __builtin_amdgcn_mfma_f32_16x16x32_bf16(af[i], bw[j], acc[i][j], 0, 0, 0);
  }
#pragma unroll
  for (int i = 0; i < 4; ++i) {
    int row = m0 + wm + (i << 4) + ((lane >> 4) << 2);
#pragma unroll
    for (int j = 0; j < 4; ++j) {
      int col = n0 + wn + (j << 4) + lr;
      float bv = bias[col];
#pragma unroll
      for (int r = 0; r < 4; ++r) {
        float v = acc[i][j][r] + bv;
        if (EPI) {
          v = tanhf(v * invS * g[col] + bb[col]);
          Cb[(size_t)(row + r) * N + col] = f2bf(v);
        } else {
          Cf[(size_t)(row + r) * N + col] = v;
        }
      }
    }
  }
}

// ---------------- launcher ----------------
extern "C" void kernel_launch(void* const* d_in, const int* in_sizes, int n_in,
                              void* d_out, int out_size, void* d_ws, size_t ws_size,
                              hipStream_t stream) {
  const int*   tokens = (const int*)d_in[0];
  const float* h0    = (const float*)d_in[1];
  const float* c0    = (const float*)d_in[2];
  const float* embW  = (const float*)d_in[3];
  const float* rWih  = (const float*)d_in[4];
  const float* rWhh  = (const float*)d_in[5];
  const float* rb    = (const float*)d_in[6];
  const float* sWih  = (const float*)d_in[7];
  const float* sWhh  = (const float*)d_in[8];
  const float* sbv   = (const float*)d_in[9];
  const float* mWih  = (const float*)d_in[10];
  const float* mWhh  = (const float*)d_in[11];
  const float* mb    = (const float*)d_in[12];
  const float* piW1  = (const float*)d_in[13];
  const float* pib1  = (const float*)d_in[14];
  const float* pilng = (const float*)d_in[15];
  const float* pilnb = (const float*)d_in[16];
  const float* piW2  = (const float*)d_in[17];
  const float* pib2  = (const float*)d_in[18];
  const float* predW = (const float*)d_in[19];
  const float* predb = (const float*)d_in[20];
  const float* bng   = (const float*)d_in[21];
  const float* bnb   = (const float*)d_in[22];
  const float* decW  = (const float*)d_in[23];
  const float* decb  = (const float*)d_in[24];
  float* out = (float*)d_out;
  float* ws  = (float*)d_ws;

  float* emb   = ws;                          // 2,097,152 f
  float* u0    = emb + 2097152;               //    65,536 f
  float* u1    = u0 + 65536;                  //    65,536 f
  float* cbuf  = u1 + 65536;                  //    32,768 f
  float* stack = cbuf + 32768;                //    65,536 f
  float* Gpart = stack + 65536;               // 1,638,400 f (4 x 32 x 12800)
  unsigned short* outsb  = (unsigned short*)(Gpart + 1638400);  // 4,194,304 us
  unsigned short* ytbf   = outsb + 4194304;                     // 2,097,152 us
  unsigned short* predWb = ytbf + 2097152;                      //   524,288 us
  unsigned short* decWb  = predWb + 524288;                     // 16,384,000 us
  int* depth = (int*)(decWb + 16384000);

  init_state<<<dim3(256), dim3(256), 0, stream>>>(h0, c0, u0, cbuf, stack, depth);
  embed_kernel<<<dim3(4096), dim3(128), 0, stream>>>(tokens, embW, emb);
  to_bf16<<<dim3(512), dim3(256), 0, stream>>>(predW, predWb, 131072);
  to_bf16<<<dim3(16000), dim3(256), 0, stream>>>(decW, decWb, 4096000);

  for (int t = 0; t < 128; ++t) {
    float* ucur = (t & 1) ? u1 : u0;
    float* unxt = (t & 1) ? u0 : u1;
    gates_gemm<<<dim3(200, 4), dim3(128), 0, stream>>>(
        t, ucur, emb, Gpart, rWih, rWhh, sWih, sWhh, mWih, mWhh, piW1);
    step_pointwise<<<dim3(32), dim3(256), 0, stream>>>(
        t, Gpart, unxt, cbuf, stack, depth, outsb,
        rb, sbv, mb, pib1, pilng, pilnb, piW2, pib2);
  }

  float invS = 1.0f / sqrtf(1.0f + 1e-5f);
  // y = tanh((outs @ predW^T + predb) * invS * bn_g + bn_b) -> ytbf (4096,512) bf16
  mfma_gemm<1><<<dim3(4, 32), dim3(256), 0, stream>>>(
      outsb, predWb, predb, 1024, 512, nullptr, ytbf, bng, bnb, invS);
  // dec = yt @ decW^T + decb -> out (4096,32000) fp32
  mfma_gemm<0><<<dim3(250, 32), dim3(256), 0, stream>>>(
      ytbf, decWb, decb, 512, 32000, out, nullptr, nullptr, nullptr, 0.0f);
  final_copy<<<dim3(128), dim3(256), 0, stream>>>(u0, cbuf, out);
}